// Round 2
// baseline (5813.266 us; speedup 1.0000x reference)
//
#include <hip/hip_runtime.h>
#include <hip/hip_bf16.h>
#include <hip/hip_fp16.h>
#include <stdint.h>

// LSTMModelLite: B=128,T=512,F=784,H=256,C=10
// R5: 2-WG-per-group fence-free persistent scan (was 4-WG).
//   - 16 WGs = 8 batch-groups x 2 WGs of 512 thr (gr=bid&7 -> same XCD pair)
//   - WG g owns h-cols [128g,128g+128); all 4 gates of a col in one lane
//   - K-split MFMA: own k-slices (ks=4g..4g+3) issued BEFORE peer poll
//     -> publish->L2 visibility hidden under own-write+barrier+own-MFMA
//   - 1 peer, 2 poll words/thread, branchless poll (both loads in flight)
//   - h exchange: RELAXED agent-scope u64 atomics, tag embedded, parity dbuf
//   - own pub words zeroed at entry (kills garbage-tag collision window)
// ws: xw 134217728 | pub 262144 (overlay wt_hi, dead after gemm) |
//     wt_lo 1638400 | wfrag 524288

typedef __attribute__((ext_vector_type(8))) short short8;
typedef __attribute__((ext_vector_type(4))) float f32x4;

__device__ __forceinline__ unsigned short f2bf(float f) {
  union { float f; uint32_t u; } v; v.f = f;
  return (unsigned short)((v.u + 0x7fffu + ((v.u >> 16) & 1u)) >> 16);
}
__device__ __forceinline__ float bfu2f(uint32_t u16) {
  union { uint32_t u; float f; } v; v.u = u16 << 16; return v.f;
}
__device__ __forceinline__ float sigm(float x) { return 1.f / (1.f + __expf(-x)); }
__device__ __forceinline__ float tanh_(float x) {
  float e = __expf(2.f * x);
  return 1.f - 2.f / (e + 1.f);
}

__global__ void repack_w(const float* __restrict__ w, unsigned short* __restrict__ wt_hi,
                         unsigned short* __restrict__ wt_lo) {
  int idx = blockIdx.x * 256 + threadIdx.x;  // n*800 + k
  if (idx >= 1024 * 800) return;
  int n = idx / 800, k = idx - n * 800;
  float v = (k < 784) ? w[k * 1024 + n] : 0.f;
  unsigned short hi = f2bf(v);
  wt_hi[idx] = hi;
  wt_lo[idx] = f2bf(v - bfu2f(hi));
}

// rec_kernel fp32 [256 k][1024 n] -> B-frags indexed (g,w,G,ks,lane,8)
// g in [0,2): WG column-half; w in [0,8): wave
__global__ void repack_wf(const float* __restrict__ rk, unsigned short* __restrict__ wf) {
  int idx = blockIdx.x * 256 + threadIdx.x;  // 2g*8w*4G*8ks*64lane = 32768
  if (idx >= 32768) return;
  int lane = idx & 63, ks = (idx >> 6) & 7, G = (idx >> 9) & 3;
  int w = (idx >> 11) & 7, g = (idx >> 14) & 1;
  int ncol = G * 256 + g * 128 + 16 * w + (lane & 15);
  int kb = ks * 32 + ((lane >> 4) << 3);
  union { unsigned short s[8]; uint4 v; } u;
  #pragma unroll
  for (int e = 0; e < 8; ++e) u.s[e] = f2bf(rk[(size_t)(kb + e) * 1024 + ncol]);
  ((uint4*)wf)[idx] = u.v;
}

// ---- xw = x @ kernel ; BM=BN=128, BK=32, 256 thr, B split hi+lo (2 MFMAs) ----
__global__ __launch_bounds__(256, 2) void gemm_xw(
    const float* __restrict__ x, const unsigned short* __restrict__ wt_hi,
    const unsigned short* __restrict__ wt_lo, __half* __restrict__ xw) {
  __shared__ __align__(16) unsigned short As[128][40];
  __shared__ __align__(16) unsigned short Bh[128][40];
  __shared__ __align__(16) unsigned short Bl[128][40];
  const int tid = threadIdx.x;
  const int m0 = blockIdx.y << 7;
  const int n0 = blockIdx.x << 7;
  const int lane = tid & 63, wv = tid >> 6;
  const int wr = wv >> 1, wc = wv & 1;
  const int fm = lane & 15;
  const int fkb = (lane >> 4) << 3;
  const int sr = tid >> 1, sh = (tid & 1) << 4;
  f32x4 acc[4][4];
  #pragma unroll
  for (int a = 0; a < 4; ++a)
    #pragma unroll
    for (int b = 0; b < 4; ++b) acc[a][b] = (f32x4){0.f, 0.f, 0.f, 0.f};

  const float* xsrc = x + (size_t)(m0 + sr) * 784;
  const unsigned short* bhsrc = wt_hi + (size_t)(n0 + sr) * 800;
  const unsigned short* blsrc = wt_lo + (size_t)(n0 + sr) * 800;

  for (int kt = 0; kt < 25; ++kt) {
    const int kb = (kt << 5) + sh;
    float va[16];
    if (kb + 16 <= 784) {
      const float4* s = (const float4*)(xsrc + kb);
      #pragma unroll
      for (int q = 0; q < 4; ++q) {
        float4 f = s[q];
        va[q * 4 + 0] = f.x; va[q * 4 + 1] = f.y;
        va[q * 4 + 2] = f.z; va[q * 4 + 3] = f.w;
      }
    } else {
      #pragma unroll
      for (int q = 0; q < 16; ++q) va[q] = 0.f;
    }
    uint32_t pk[8];
    #pragma unroll
    for (int q = 0; q < 8; ++q)
      pk[q] = (uint32_t)f2bf(va[2 * q]) | ((uint32_t)f2bf(va[2 * q + 1]) << 16);
    uint4* adst = (uint4*)&As[sr][sh];
    adst[0] = make_uint4(pk[0], pk[1], pk[2], pk[3]);
    adst[1] = make_uint4(pk[4], pk[5], pk[6], pk[7]);
    const uint4* bh4 = (const uint4*)(bhsrc + kb);
    const uint4* bl4 = (const uint4*)(blsrc + kb);
    uint4* bhd = (uint4*)&Bh[sr][sh];
    uint4* bld = (uint4*)&Bl[sr][sh];
    bhd[0] = bh4[0]; bhd[1] = bh4[1];
    bld[0] = bl4[0]; bld[1] = bl4[1];
    __syncthreads();

    short8 af[4], bh[4], bl[4];
    #pragma unroll
    for (int mt = 0; mt < 4; ++mt)
      af[mt] = *(const short8*)&As[(wr << 6) + (mt << 4) + fm][fkb];
    #pragma unroll
    for (int nt = 0; nt < 4; ++nt) {
      bh[nt] = *(const short8*)&Bh[(wc << 6) + (nt << 4) + fm][fkb];
      bl[nt] = *(const short8*)&Bl[(wc << 6) + (nt << 4) + fm][fkb];
    }
    #pragma unroll
    for (int mt = 0; mt < 4; ++mt)
      #pragma unroll
      for (int nt = 0; nt < 4; ++nt) {
        acc[mt][nt] = __builtin_amdgcn_mfma_f32_16x16x32_bf16(af[mt], bh[nt], acc[mt][nt], 0, 0, 0);
        acc[mt][nt] = __builtin_amdgcn_mfma_f32_16x16x32_bf16(af[mt], bl[nt], acc[mt][nt], 0, 0, 0);
      }
    __syncthreads();
  }
  const int rbase = (lane >> 4) << 2;
  #pragma unroll
  for (int mt = 0; mt < 4; ++mt)
    #pragma unroll
    for (int nt = 0; nt < 4; ++nt) {
      int col = n0 + (wc << 6) + (nt << 4) + fm;
      #pragma unroll
      for (int r = 0; r < 4; ++r) {
        int row = m0 + (wr << 6) + (mt << 4) + rbase + r;
        xw[(size_t)row * 1024 + col] = __float2half(acc[mt][nt][r]);
      }
    }
}

// ---- fence-free persistent recurrent scan (2 WGs/group, K-split MFMA) ----
__global__ __launch_bounds__(512, 2) void scan_kernel(
    const unsigned short* __restrict__ wf, __half* __restrict__ xw,
    unsigned long long* __restrict__ pub,
    const float* __restrict__ bias, const float* __restrict__ wci,
    const float* __restrict__ wcf, const float* __restrict__ wco,
    const float* __restrict__ gamma, const float* __restrict__ beta,
    const float* __restrict__ mean, const float* __restrict__ var) {
  __shared__ __align__(16) unsigned short h_all[16][264];
  const int tid = threadIdx.x, lane = tid & 63, w = tid >> 6;  // w in [0,8)
  const int gr = blockIdx.x & 7;   // batch-group (same XCD via %8 round-robin)
  const int g = blockIdx.x >> 3;   // column-half: owns jg in [128g, 128g+128)
  const int c = lane & 15, q = lane >> 4;
  const int jj = 16 * w + c;       // [0,128) within half
  const int jg = 128 * g + jj;     // [0,256) h column
  const int pbase = 128 - 128 * g; // peer half base
  const int ksO = 4 * g;           // own k-slice base (h rows 128g..)
  const int ksP = 4 - 4 * g;       // peer k-slice base

  // resident weight B-frags: tile (G,w) cols G*256+128g+16w+[0,16), all 8 ks
  short8 bw[4][8];
  {
    const unsigned short* wb = wf + (size_t)(g * 8 + w) * 16384;
    #pragma unroll
    for (int G = 0; G < 4; ++G)
      #pragma unroll
      for (int ks = 0; ks < 8; ++ks)
        bw[G][ks] = *(const short8*)(wb + (size_t)((G * 8 + ks) * 64 + lane) * 8);
  }

  const float b0 = bias[jg], b1 = bias[256 + jg], b2 = bias[512 + jg], b3 = bias[768 + jg];
  const float pci = wci[jg], pcf = wcf[jg], pco = wco[jg];
  const float bna = gamma[jg] * rsqrtf(var[jg] + 1e-3f);
  const float bnb = beta[jg] - mean[jg] * bna;
  float c2[4] = {0.f, 0.f, 0.f, 0.f};

  unsigned long long* mypub = pub + (size_t)(gr * 2 + g) * 1024 + jj * 8 + q * 2;
  unsigned long long* peerb = pub + (size_t)(gr * 2 + (1 - g)) * 1024 + 2 * tid;
  // zero own words (both parities): no garbage-tag collisions from wt_hi overlay
  __hip_atomic_store(mypub + 0, 0ull, __ATOMIC_RELAXED, __HIP_MEMORY_SCOPE_AGENT);
  __hip_atomic_store(mypub + 1, 0ull, __ATOMIC_RELAXED, __HIP_MEMORY_SCOPE_AGENT);
  __hip_atomic_store(mypub + 16384, 0ull, __ATOMIC_RELAXED, __HIP_MEMORY_SCOPE_AGENT);
  __hip_atomic_store(mypub + 16385, 0ull, __ATOMIC_RELAXED, __HIP_MEMORY_SCOPE_AGENT);

  const size_t xbase = ((size_t)(gr * 16 + 4 * q) << 9);  // row of batch 4q, t=0

  // prefetch xw for s=0
  float xp[4][4];
  #pragma unroll
  for (int G = 0; G < 4; ++G)
    #pragma unroll
    for (int r = 0; r < 4; ++r)
      xp[G][r] = __half2float(xw[((xbase + ((size_t)r << 9)) << 10) + G * 256 + jg]);

  for (int s = 0; s < 512; ++s) {
    f32x4 acc[4];
    #pragma unroll
    for (int G = 0; G < 4; ++G) acc[G] = (f32x4){0.f, 0.f, 0.f, 0.f};

    if (s > 0) {
      // (A) own-half MFMA first: own h already in h_all (barrier at loop end)
      short8 af[4];
      #pragma unroll
      for (int k4 = 0; k4 < 4; ++k4)
        af[k4] = *(const short8*)&h_all[c][(ksO + k4) * 32 + q * 8];
      #pragma unroll
      for (int k4 = 0; k4 < 4; ++k4)
        #pragma unroll
        for (int G = 0; G < 4; ++G)
          acc[G] = __builtin_amdgcn_mfma_f32_16x16x32_bf16(af[k4], bw[G][ksO + k4], acc[G], 0, 0, 0);

      // (B) poll single peer, 2 words, branchless (both loads in flight)
      const size_t slot = (size_t)(s & 1) * 16384;
      unsigned long long v0, v1;
      long cnt = 0;
      for (;;) {
        v0 = __hip_atomic_load(peerb + slot, __ATOMIC_RELAXED, __HIP_MEMORY_SCOPE_AGENT);
        v1 = __hip_atomic_load(peerb + slot + 1, __ATOMIC_RELAXED, __HIP_MEMORY_SCOPE_AGENT);
        if ((unsigned)(v0 >> 32) == (unsigned)s && (unsigned)(v1 >> 32) == (unsigned)s) break;
        if (++cnt > (1L << 22)) break;  // bounded: no infinite hang
      }
      // (C) stage peer h: word wid=2*tid(+1) -> col tid>>2, batches 4*(tid&3)..+3
      {
        const int jj2 = tid >> 2, q2 = tid & 3;
        const int m0 = 4 * q2, col = pbase + jj2;
        h_all[m0 + 0][col] = (unsigned short)(v0 & 0xffffu);
        h_all[m0 + 1][col] = (unsigned short)((v0 >> 16) & 0xffffu);
        h_all[m0 + 2][col] = (unsigned short)(v1 & 0xffffu);
        h_all[m0 + 3][col] = (unsigned short)((v1 >> 16) & 0xffffu);
      }
      __syncthreads();  // BAR-A: peer h visible
      // (D) peer-half MFMA
      #pragma unroll
      for (int k4 = 0; k4 < 4; ++k4)
        af[k4] = *(const short8*)&h_all[c][(ksP + k4) * 32 + q * 8];
      #pragma unroll
      for (int k4 = 0; k4 < 4; ++k4)
        #pragma unroll
        for (int G = 0; G < 4; ++G)
          acc[G] = __builtin_amdgcn_mfma_f32_16x16x32_bf16(af[k4], bw[G][ksP + k4], acc[G], 0, 0, 0);
    }

    // gates, directly in C-layout: lane owns (jg, batches 4q..4q+3)
    float hn[4];
    #pragma unroll
    for (int r = 0; r < 4; ++r) {
      float z0 = acc[0][r] + b0 + xp[0][r];
      float z1 = acc[1][r] + b1 + xp[1][r];
      float z2 = acc[2][r] + b2 + xp[2][r];
      float z3 = acc[3][r] + b3 + xp[3][r];
      float ig = sigm(z0 + c2[r] * pci);
      float fg = sigm(z1 + c2[r] * pcf);
      float cn = fg * c2[r] + ig * tanh_(z2);
      float og = sigm(z3 + cn * pco);
      float h = og * tanh_(cn);
      c2[r] = cn;
      hn[r] = h;
      if ((r & 1) && s < 511) {  // publish pair ASAP: overlaps remaining gates
        unsigned long long pv =
            ((unsigned long long)(unsigned)(s + 1) << 32) |
            (unsigned long long)(((uint32_t)f2bf(hn[r - 1])) |
                                 ((uint32_t)f2bf(hn[r]) << 16));
        __hip_atomic_store(mypub + (size_t)((s + 1) & 1) * 16384 + (r >> 1), pv,
                           __ATOMIC_RELAXED, __HIP_MEMORY_SCOPE_AGENT);
      }
    }
    // stage own h into own region (read by own-half MFMA next step)
    #pragma unroll
    for (int r = 0; r < 4; ++r) h_all[4 * q + r][jg] = f2bf(hn[r]);
    // y = tanh(BN(h)) -> xw col jg (final FC reads later)
    #pragma unroll
    for (int r = 0; r < 4; ++r) {
      float y = tanh_(hn[r] * bna + bnb);
      xw[((xbase + ((size_t)r << 9) + s) << 10) + jg] = __float2half(y);
    }
    // prefetch xw for s+1 (latency hidden under next step's poll/MFMA)
    if (s < 511) {
      #pragma unroll
      for (int G = 0; G < 4; ++G)
        #pragma unroll
        for (int r = 0; r < 4; ++r)
          xp[G][r] = __half2float(
              xw[((xbase + ((size_t)r << 9) + (s + 1)) << 10) + G * 256 + jg]);
    }
    __syncthreads();  // BAR-B: own h visible for next step's own-half MFMA
  }
}

// ---- final FC: out[b,t,c] = sum_j y[b,t,j] * fcw[j,c]; wave per row ----
__global__ __launch_bounds__(256) void final_fc(const __half* __restrict__ xw,
                                                const float* __restrict__ fcw,
                                                float* __restrict__ out) {
  const int tid = threadIdx.x, lane = tid & 63, w = tid >> 6;
  const int wid = blockIdx.x * 4 + w;  // 512 waves
  float fw[4][10];
  #pragma unroll
  for (int q = 0; q < 4; ++q)
    #pragma unroll
    for (int c = 0; c < 10; ++c) fw[q][c] = fcw[(lane * 4 + q) * 10 + c];
  for (int it = 0; it < 128; ++it) {
    const int row = it * 512 + wid;
    uint2 u = *(const uint2*)(xw + ((size_t)row << 10) + lane * 4);
    const __half* hp = (const __half*)&u;
    float y0 = __half2float(hp[0]), y1 = __half2float(hp[1]);
    float y2 = __half2float(hp[2]), y3 = __half2float(hp[3]);
    float p[10];
    #pragma unroll
    for (int c = 0; c < 10; ++c)
      p[c] = y0 * fw[0][c] + y1 * fw[1][c] + y2 * fw[2][c] + y3 * fw[3][c];
    #pragma unroll
    for (int off = 1; off < 64; off <<= 1)
      #pragma unroll
      for (int c = 0; c < 10; ++c) p[c] += __shfl_xor(p[c], off, 64);
    if (lane == 0) {
      #pragma unroll
      for (int c = 0; c < 10; ++c) out[(size_t)row * 10 + c] = p[c];
    }
  }
}

extern "C" void kernel_launch(void* const* d_in, const int* in_sizes, int n_in,
                              void* d_out, int out_size, void* d_ws, size_t ws_size,
                              hipStream_t stream) {
  const float* x     = (const float*)d_in[0];
  const float* kw    = (const float*)d_in[1];
  const float* rk    = (const float*)d_in[2];
  const float* bias  = (const float*)d_in[3];
  const float* wci   = (const float*)d_in[4];
  const float* wcf   = (const float*)d_in[5];
  const float* wco   = (const float*)d_in[6];
  const float* gamma = (const float*)d_in[7];
  const float* beta  = (const float*)d_in[8];
  const float* mean  = (const float*)d_in[9];
  const float* var   = (const float*)d_in[10];
  const float* fcw   = (const float*)d_in[11];
  float* out = (float*)d_out;

  char* ws = (char*)d_ws;
  __half*         xw    = (__half*)ws;                                 // 134217728 B
  unsigned short* wt_hi = (unsigned short*)(ws + 134217728);           // 1638400 B
  unsigned short* wt_lo = (unsigned short*)(ws + 134217728 + 1638400); // 1638400 B
  unsigned short* wfrag = (unsigned short*)(ws + 134217728 + 3276800); // 524288 B
  // pub overlays wt_hi (dead after gemm_xw): 2 parity * 16 WG * 1024 u64 = 262144 B
  unsigned long long* pub = (unsigned long long*)(ws + 134217728);

  repack_w<<<dim3((1024 * 800 + 255) / 256), dim3(256), 0, stream>>>(kw, wt_hi, wt_lo);
  repack_wf<<<dim3(128), dim3(256), 0, stream>>>(rk, wfrag);
  gemm_xw<<<dim3(8, 512), dim3(256), 0, stream>>>(x, wt_hi, wt_lo, xw);
  scan_kernel<<<dim3(16), dim3(512), 0, stream>>>(wfrag, xw, pub, bias,
                                                  wci, wcf, wco, gamma, beta, mean, var);
  final_fc<<<dim3(128), dim3(256), 0, stream>>>(xw, fcw, out);
}

// Round 4
// 2411.104 us; speedup vs baseline: 2.4110x; 2.4110x over previous
//
#include <hip/hip_runtime.h>
#include <hip/hip_bf16.h>
#include <hip/hip_fp16.h>
#include <stdint.h>

// LSTMModelLite: B=128,T=512,F=784,H=256,C=10
// R6 = R5 structure + rule#20 fix: bw[] register indices are compile-time.
//   R5's bw[G][ksO+k4] (runtime ksO) demoted the 128-VGPR weight array to
//   scratch (VGPR_Count=52, 3x regression). Now own k-slices live in slots
//   0..3 and peer slices in 4..7 (remap at LOAD time via runtime address).
//   - 16 WGs = 8 batch-groups x 2 WGs of 512 thr (gr=bid&7 -> same XCD pair)
//   - WG g owns h-cols [128g,128g+128); all 4 gates of a col in one lane
//   - K-split MFMA: own k-slices issued BEFORE peer poll -> publish->L2
//     visibility hidden under own-write+barrier+own-MFMA
//   - 1 peer, 2 poll words/thread, branchless poll
//   - h exchange: RELAXED agent-scope u64 atomics, tag embedded, parity dbuf
// ws: xw 134217728 | pub 262144 (overlay wt_hi, dead after gemm) |
//     wt_lo 1638400 | wfrag 524288

typedef __attribute__((ext_vector_type(8))) short short8;
typedef __attribute__((ext_vector_type(4))) float f32x4;

__device__ __forceinline__ unsigned short f2bf(float f) {
  union { float f; uint32_t u; } v; v.f = f;
  return (unsigned short)((v.u + 0x7fffu + ((v.u >> 16) & 1u)) >> 16);
}
__device__ __forceinline__ float bfu2f(uint32_t u16) {
  union { uint32_t u; float f; } v; v.u = u16 << 16; return v.f;
}
__device__ __forceinline__ float sigm(float x) { return 1.f / (1.f + __expf(-x)); }
__device__ __forceinline__ float tanh_(float x) {
  float e = __expf(2.f * x);
  return 1.f - 2.f / (e + 1.f);
}

__global__ void repack_w(const float* __restrict__ w, unsigned short* __restrict__ wt_hi,
                         unsigned short* __restrict__ wt_lo) {
  int idx = blockIdx.x * 256 + threadIdx.x;  // n*800 + k
  if (idx >= 1024 * 800) return;
  int n = idx / 800, k = idx - n * 800;
  float v = (k < 784) ? w[k * 1024 + n] : 0.f;
  unsigned short hi = f2bf(v);
  wt_hi[idx] = hi;
  wt_lo[idx] = f2bf(v - bfu2f(hi));
}

// rec_kernel fp32 [256 k][1024 n] -> B-frags indexed (g,w,G,ks,lane,8)
// g in [0,2): WG column-half; w in [0,8): wave
__global__ void repack_wf(const float* __restrict__ rk, unsigned short* __restrict__ wf) {
  int idx = blockIdx.x * 256 + threadIdx.x;  // 2g*8w*4G*8ks*64lane = 32768
  if (idx >= 32768) return;
  int lane = idx & 63, ks = (idx >> 6) & 7, G = (idx >> 9) & 3;
  int w = (idx >> 11) & 7, g = (idx >> 14) & 1;
  int ncol = G * 256 + g * 128 + 16 * w + (lane & 15);
  int kb = ks * 32 + ((lane >> 4) << 3);
  union { unsigned short s[8]; uint4 v; } u;
  #pragma unroll
  for (int e = 0; e < 8; ++e) u.s[e] = f2bf(rk[(size_t)(kb + e) * 1024 + ncol]);
  ((uint4*)wf)[idx] = u.v;
}

// ---- xw = x @ kernel ; BM=BN=128, BK=32, 256 thr, B split hi+lo (2 MFMAs) ----
__global__ __launch_bounds__(256, 2) void gemm_xw(
    const float* __restrict__ x, const unsigned short* __restrict__ wt_hi,
    const unsigned short* __restrict__ wt_lo, __half* __restrict__ xw) {
  __shared__ __align__(16) unsigned short As[128][40];
  __shared__ __align__(16) unsigned short Bh[128][40];
  __shared__ __align__(16) unsigned short Bl[128][40];
  const int tid = threadIdx.x;
  const int m0 = blockIdx.y << 7;
  const int n0 = blockIdx.x << 7;
  const int lane = tid & 63, wv = tid >> 6;
  const int wr = wv >> 1, wc = wv & 1;
  const int fm = lane & 15;
  const int fkb = (lane >> 4) << 3;
  const int sr = tid >> 1, sh = (tid & 1) << 4;
  f32x4 acc[4][4];
  #pragma unroll
  for (int a = 0; a < 4; ++a)
    #pragma unroll
    for (int b = 0; b < 4; ++b) acc[a][b] = (f32x4){0.f, 0.f, 0.f, 0.f};

  const float* xsrc = x + (size_t)(m0 + sr) * 784;
  const unsigned short* bhsrc = wt_hi + (size_t)(n0 + sr) * 800;
  const unsigned short* blsrc = wt_lo + (size_t)(n0 + sr) * 800;

  for (int kt = 0; kt < 25; ++kt) {
    const int kb = (kt << 5) + sh;
    float va[16];
    if (kb + 16 <= 784) {
      const float4* s = (const float4*)(xsrc + kb);
      #pragma unroll
      for (int q = 0; q < 4; ++q) {
        float4 f = s[q];
        va[q * 4 + 0] = f.x; va[q * 4 + 1] = f.y;
        va[q * 4 + 2] = f.z; va[q * 4 + 3] = f.w;
      }
    } else {
      #pragma unroll
      for (int q = 0; q < 16; ++q) va[q] = 0.f;
    }
    uint32_t pk[8];
    #pragma unroll
    for (int q = 0; q < 8; ++q)
      pk[q] = (uint32_t)f2bf(va[2 * q]) | ((uint32_t)f2bf(va[2 * q + 1]) << 16);
    uint4* adst = (uint4*)&As[sr][sh];
    adst[0] = make_uint4(pk[0], pk[1], pk[2], pk[3]);
    adst[1] = make_uint4(pk[4], pk[5], pk[6], pk[7]);
    const uint4* bh4 = (const uint4*)(bhsrc + kb);
    const uint4* bl4 = (const uint4*)(blsrc + kb);
    uint4* bhd = (uint4*)&Bh[sr][sh];
    uint4* bld = (uint4*)&Bl[sr][sh];
    bhd[0] = bh4[0]; bhd[1] = bh4[1];
    bld[0] = bl4[0]; bld[1] = bl4[1];
    __syncthreads();

    short8 af[4], bh[4], bl[4];
    #pragma unroll
    for (int mt = 0; mt < 4; ++mt)
      af[mt] = *(const short8*)&As[(wr << 6) + (mt << 4) + fm][fkb];
    #pragma unroll
    for (int nt = 0; nt < 4; ++nt) {
      bh[nt] = *(const short8*)&Bh[(wc << 6) + (nt << 4) + fm][fkb];
      bl[nt] = *(const short8*)&Bl[(wc << 6) + (nt << 4) + fm][fkb];
    }
    #pragma unroll
    for (int mt = 0; mt < 4; ++mt)
      #pragma unroll
      for (int nt = 0; nt < 4; ++nt) {
        acc[mt][nt] = __builtin_amdgcn_mfma_f32_16x16x32_bf16(af[mt], bh[nt], acc[mt][nt], 0, 0, 0);
        acc[mt][nt] = __builtin_amdgcn_mfma_f32_16x16x32_bf16(af[mt], bl[nt], acc[mt][nt], 0, 0, 0);
      }
    __syncthreads();
  }
  const int rbase = (lane >> 4) << 2;
  #pragma unroll
  for (int mt = 0; mt < 4; ++mt)
    #pragma unroll
    for (int nt = 0; nt < 4; ++nt) {
      int col = n0 + (wc << 6) + (nt << 4) + fm;
      #pragma unroll
      for (int r = 0; r < 4; ++r) {
        int row = m0 + (wr << 6) + (mt << 4) + rbase + r;
        xw[(size_t)row * 1024 + col] = __float2half(acc[mt][nt][r]);
      }
    }
}

// ---- fence-free persistent recurrent scan (2 WGs/group, K-split MFMA) ----
__global__ __launch_bounds__(512, 2) void scan_kernel(
    const unsigned short* __restrict__ wf, __half* __restrict__ xw,
    unsigned long long* __restrict__ pub,
    const float* __restrict__ bias, const float* __restrict__ wci,
    const float* __restrict__ wcf, const float* __restrict__ wco,
    const float* __restrict__ gamma, const float* __restrict__ beta,
    const float* __restrict__ mean, const float* __restrict__ var) {
  __shared__ __align__(16) unsigned short h_all[16][264];
  const int tid = threadIdx.x, lane = tid & 63, w = tid >> 6;  // w in [0,8)
  const int gr = blockIdx.x & 7;   // batch-group (same XCD via %8 round-robin)
  const int g = blockIdx.x >> 3;   // column-half: owns jg in [128g, 128g+128)
  const int c = lane & 15, q = lane >> 4;
  const int jj = 16 * w + c;       // [0,128) within half
  const int jg = 128 * g + jj;     // [0,256) h column
  const int pbase = 128 - 128 * g; // peer half base
  const int ksO = 4 * g;           // own k-slice base (h rows 128g..)
  const int ksP = 4 - 4 * g;       // peer k-slice base

  // resident weight B-frags, STATIC register slots (rule #20):
  //   slot 0..3 = own k-slices (ksO+slot), slot 4..7 = peer (ksP+slot-4).
  //   Runtime ksO/ksP only in the LOAD ADDRESS, never in the register index.
  short8 bw[4][8];
  {
    const unsigned short* wb = wf + (size_t)(g * 8 + w) * 16384;
    #pragma unroll
    for (int G = 0; G < 4; ++G)
      #pragma unroll
      for (int k4 = 0; k4 < 4; ++k4) {
        bw[G][k4]     = *(const short8*)(wb + (size_t)((G * 8 + ksO + k4) * 64 + lane) * 8);
        bw[G][4 + k4] = *(const short8*)(wb + (size_t)((G * 8 + ksP + k4) * 64 + lane) * 8);
      }
  }

  const float b0 = bias[jg], b1 = bias[256 + jg], b2 = bias[512 + jg], b3 = bias[768 + jg];
  const float pci = wci[jg], pcf = wcf[jg], pco = wco[jg];
  const float bna = gamma[jg] * rsqrtf(var[jg] + 1e-3f);
  const float bnb = beta[jg] - mean[jg] * bna;
  float c2[4] = {0.f, 0.f, 0.f, 0.f};

  unsigned long long* mypub = pub + (size_t)(gr * 2 + g) * 1024 + jj * 8 + q * 2;
  unsigned long long* peerb = pub + (size_t)(gr * 2 + (1 - g)) * 1024 + 2 * tid;
  // zero own words (both parities): no garbage-tag collisions from wt_hi overlay
  __hip_atomic_store(mypub + 0, 0ull, __ATOMIC_RELAXED, __HIP_MEMORY_SCOPE_AGENT);
  __hip_atomic_store(mypub + 1, 0ull, __ATOMIC_RELAXED, __HIP_MEMORY_SCOPE_AGENT);
  __hip_atomic_store(mypub + 16384, 0ull, __ATOMIC_RELAXED, __HIP_MEMORY_SCOPE_AGENT);
  __hip_atomic_store(mypub + 16385, 0ull, __ATOMIC_RELAXED, __HIP_MEMORY_SCOPE_AGENT);

  const size_t xbase = ((size_t)(gr * 16 + 4 * q) << 9);  // row of batch 4q, t=0

  // prefetch xw for s=0
  float xp[4][4];
  #pragma unroll
  for (int G = 0; G < 4; ++G)
    #pragma unroll
    for (int r = 0; r < 4; ++r)
      xp[G][r] = __half2float(xw[((xbase + ((size_t)r << 9)) << 10) + G * 256 + jg]);

  for (int s = 0; s < 512; ++s) {
    f32x4 acc[4];
    #pragma unroll
    for (int G = 0; G < 4; ++G) acc[G] = (f32x4){0.f, 0.f, 0.f, 0.f};

    if (s > 0) {
      // (A) own-half MFMA first: own h already in h_all (barrier at loop end)
      short8 af[4];
      #pragma unroll
      for (int k4 = 0; k4 < 4; ++k4)
        af[k4] = *(const short8*)&h_all[c][(ksO + k4) * 32 + q * 8];
      #pragma unroll
      for (int k4 = 0; k4 < 4; ++k4)
        #pragma unroll
        for (int G = 0; G < 4; ++G)
          acc[G] = __builtin_amdgcn_mfma_f32_16x16x32_bf16(af[k4], bw[G][k4], acc[G], 0, 0, 0);

      // (B) poll single peer, 2 words, branchless (both loads in flight)
      const size_t slot = (size_t)(s & 1) * 16384;
      unsigned long long v0, v1;
      long cnt = 0;
      for (;;) {
        v0 = __hip_atomic_load(peerb + slot, __ATOMIC_RELAXED, __HIP_MEMORY_SCOPE_AGENT);
        v1 = __hip_atomic_load(peerb + slot + 1, __ATOMIC_RELAXED, __HIP_MEMORY_SCOPE_AGENT);
        if ((unsigned)(v0 >> 32) == (unsigned)s && (unsigned)(v1 >> 32) == (unsigned)s) break;
        if (++cnt > (1L << 22)) break;  // bounded: no infinite hang
      }
      // (C) stage peer h: word wid=2*tid(+1) -> col tid>>2, batches 4*(tid&3)..+3
      {
        const int jj2 = tid >> 2, q2 = tid & 3;
        const int m0 = 4 * q2, col = pbase + jj2;
        h_all[m0 + 0][col] = (unsigned short)(v0 & 0xffffu);
        h_all[m0 + 1][col] = (unsigned short)((v0 >> 16) & 0xffffu);
        h_all[m0 + 2][col] = (unsigned short)(v1 & 0xffffu);
        h_all[m0 + 3][col] = (unsigned short)((v1 >> 16) & 0xffffu);
      }
      __syncthreads();  // BAR-A: peer h visible
      // (D) peer-half MFMA (static slots 4..7)
      #pragma unroll
      for (int k4 = 0; k4 < 4; ++k4)
        af[k4] = *(const short8*)&h_all[c][(ksP + k4) * 32 + q * 8];
      #pragma unroll
      for (int k4 = 0; k4 < 4; ++k4)
        #pragma unroll
        for (int G = 0; G < 4; ++G)
          acc[G] = __builtin_amdgcn_mfma_f32_16x16x32_bf16(af[k4], bw[G][4 + k4], acc[G], 0, 0, 0);
    }

    // gates, directly in C-layout: lane owns (jg, batches 4q..4q+3)
    float hn[4];
    #pragma unroll
    for (int r = 0; r < 4; ++r) {
      float z0 = acc[0][r] + b0 + xp[0][r];
      float z1 = acc[1][r] + b1 + xp[1][r];
      float z2 = acc[2][r] + b2 + xp[2][r];
      float z3 = acc[3][r] + b3 + xp[3][r];
      float ig = sigm(z0 + c2[r] * pci);
      float fg = sigm(z1 + c2[r] * pcf);
      float cn = fg * c2[r] + ig * tanh_(z2);
      float og = sigm(z3 + cn * pco);
      float h = og * tanh_(cn);
      c2[r] = cn;
      hn[r] = h;
      if ((r & 1) && s < 511) {  // publish pair ASAP: overlaps remaining gates
        unsigned long long pv =
            ((unsigned long long)(unsigned)(s + 1) << 32) |
            (unsigned long long)(((uint32_t)f2bf(hn[r - 1])) |
                                 ((uint32_t)f2bf(hn[r]) << 16));
        __hip_atomic_store(mypub + (size_t)((s + 1) & 1) * 16384 + (r >> 1), pv,
                           __ATOMIC_RELAXED, __HIP_MEMORY_SCOPE_AGENT);
      }
    }
    // stage own h into own region (read by own-half MFMA next step)
    #pragma unroll
    for (int r = 0; r < 4; ++r) h_all[4 * q + r][jg] = f2bf(hn[r]);
    // y = tanh(BN(h)) -> xw col jg (final FC reads later)
    #pragma unroll
    for (int r = 0; r < 4; ++r) {
      float y = tanh_(hn[r] * bna + bnb);
      xw[((xbase + ((size_t)r << 9) + s) << 10) + jg] = __float2half(y);
    }
    // prefetch xw for s+1 (latency hidden under next step's poll/MFMA)
    if (s < 511) {
      #pragma unroll
      for (int G = 0; G < 4; ++G)
        #pragma unroll
        for (int r = 0; r < 4; ++r)
          xp[G][r] = __half2float(
              xw[((xbase + ((size_t)r << 9) + (s + 1)) << 10) + G * 256 + jg]);
    }
    __syncthreads();  // BAR-B: own h visible for next step's own-half MFMA
  }
}

// ---- final FC: out[b,t,c] = sum_j y[b,t,j] * fcw[j,c]; wave per row ----
__global__ __launch_bounds__(256) void final_fc(const __half* __restrict__ xw,
                                                const float* __restrict__ fcw,
                                                float* __restrict__ out) {
  const int tid = threadIdx.x, lane = tid & 63, w = tid >> 6;
  const int wid = blockIdx.x * 4 + w;  // 512 waves
  float fw[4][10];
  #pragma unroll
  for (int q = 0; q < 4; ++q)
    #pragma unroll
    for (int c = 0; c < 10; ++c) fw[q][c] = fcw[(lane * 4 + q) * 10 + c];
  for (int it = 0; it < 128; ++it) {
    const int row = it * 512 + wid;
    uint2 u = *(const uint2*)(xw + ((size_t)row << 10) + lane * 4);
    const __half* hp = (const __half*)&u;
    float y0 = __half2float(hp[0]), y1 = __half2float(hp[1]);
    float y2 = __half2float(hp[2]), y3 = __half2float(hp[3]);
    float p[10];
    #pragma unroll
    for (int c = 0; c < 10; ++c)
      p[c] = y0 * fw[0][c] + y1 * fw[1][c] + y2 * fw[2][c] + y3 * fw[3][c];
    #pragma unroll
    for (int off = 1; off < 64; off <<= 1)
      #pragma unroll
      for (int c = 0; c < 10; ++c) p[c] += __shfl_xor(p[c], off, 64);
    if (lane == 0) {
      #pragma unroll
      for (int c = 0; c < 10; ++c) out[(size_t)row * 10 + c] = p[c];
    }
  }
}

extern "C" void kernel_launch(void* const* d_in, const int* in_sizes, int n_in,
                              void* d_out, int out_size, void* d_ws, size_t ws_size,
                              hipStream_t stream) {
  const float* x     = (const float*)d_in[0];
  const float* kw    = (const float*)d_in[1];
  const float* rk    = (const float*)d_in[2];
  const float* bias  = (const float*)d_in[3];
  const float* wci   = (const float*)d_in[4];
  const float* wcf   = (const float*)d_in[5];
  const float* wco   = (const float*)d_in[6];
  const float* gamma = (const float*)d_in[7];
  const float* beta  = (const float*)d_in[8];
  const float* mean  = (const float*)d_in[9];
  const float* var   = (const float*)d_in[10];
  const float* fcw   = (const float*)d_in[11];
  float* out = (float*)d_out;

  char* ws = (char*)d_ws;
  __half*         xw    = (__half*)ws;                                 // 134217728 B
  unsigned short* wt_hi = (unsigned short*)(ws + 134217728);           // 1638400 B
  unsigned short* wt_lo = (unsigned short*)(ws + 134217728 + 1638400); // 1638400 B
  unsigned short* wfrag = (unsigned short*)(ws + 134217728 + 3276800); // 524288 B
  // pub overlays wt_hi (dead after gemm_xw): 2 parity * 16 WG * 1024 u64 = 262144 B
  unsigned long long* pub = (unsigned long long*)(ws + 134217728);

  repack_w<<<dim3((1024 * 800 + 255) / 256), dim3(256), 0, stream>>>(kw, wt_hi, wt_lo);
  repack_wf<<<dim3(128), dim3(256), 0, stream>>>(rk, wfrag);
  gemm_xw<<<dim3(8, 512), dim3(256), 0, stream>>>(x, wt_hi, wt_lo, xw);
  scan_kernel<<<dim3(16), dim3(512), 0, stream>>>(wfrag, xw, pub, bias,
                                                  wci, wcf, wco, gamma, beta, mean, var);
  final_fc<<<dim3(128), dim3(256), 0, stream>>>(xw, fcw, out);
}

// Round 6
// 2250.193 us; speedup vs baseline: 2.5835x; 1.0715x over previous
//
#include <hip/hip_runtime.h>
#include <hip/hip_bf16.h>
#include <hip/hip_fp16.h>
#include <stdint.h>

// LSTMModelLite: B=128,T=512,F=784,H=256,C=10
// R7: LDS-resident recurrent weights + raw barriers + rcp gates.
//   Root cause found (R4/R6 counters): bw[4][8] = 128 VGPRs NEVER fit
//   (VGPR_Count 124/112) -> every step reloaded B-frags from scratch,
//   ~32 x ~250cyc serialized = the ~3.3us/step wall in ALL prior versions.
//   Fix: Wr slice (128 KB/WG) lives in LDS; ds_read_b128 -> MFMA is the
//   compiler's well-scheduled path. Exchange protocol = R4 verbatim
//   (32 WGs = 8 groups x 4, parity-tagged relaxed u64, 3 peers).
//   Raw s_barrier (lgkmcnt-only) removes the per-step vmcnt(0) drain of
//   the 16 xw-prefetch loads; rcpf removes full-div sequences in gates.
// ws: xw 134217728 | pub 262144 (overlay wt_hi, dead after gemm) |
//     wt_lo 1638400 | wfrag 524288

typedef __attribute__((ext_vector_type(8))) short short8;
typedef __attribute__((ext_vector_type(4))) float f32x4;

__device__ __forceinline__ unsigned short f2bf(float f) {
  union { float f; uint32_t u; } v; v.f = f;
  return (unsigned short)((v.u + 0x7fffu + ((v.u >> 16) & 1u)) >> 16);
}
__device__ __forceinline__ float bfu2f(uint32_t u16) {
  union { uint32_t u; float f; } v; v.u = u16 << 16; return v.f;
}
__device__ __forceinline__ float sigm(float x) {
  return __builtin_amdgcn_rcpf(1.f + __expf(-x));
}
__device__ __forceinline__ float tanh_(float x) {
  float e = __expf(2.f * x);
  return 1.f - 2.f * __builtin_amdgcn_rcpf(e + 1.f);
}
// raw barrier: waits LDS ops only; vmem (y stores, xw prefetch, pub) stays
// in flight across it. memory-clobber sandwich pins compiler ordering.
__device__ __forceinline__ void bar_raw() {
  asm volatile("s_waitcnt lgkmcnt(0)" ::: "memory");
  __builtin_amdgcn_s_barrier();
  asm volatile("" ::: "memory");
}

__global__ void repack_w(const float* __restrict__ w, unsigned short* __restrict__ wt_hi,
                         unsigned short* __restrict__ wt_lo) {
  int idx = blockIdx.x * 256 + threadIdx.x;  // n*800 + k
  if (idx >= 1024 * 800) return;
  int n = idx / 800, k = idx - n * 800;
  float v = (k < 784) ? w[k * 1024 + n] : 0.f;
  unsigned short hi = f2bf(v);
  wt_hi[idx] = hi;
  wt_lo[idx] = f2bf(v - bfu2f(hi));
}

// rec_kernel fp32 [256 k][1024 n] -> B-frags indexed (g,w,G,ks,lane,8)
// g in [0,4): WG; w in [0,4): wave   (R4 layout, verbatim)
__global__ void repack_wf(const float* __restrict__ rk, unsigned short* __restrict__ wf) {
  int idx = blockIdx.x * 256 + threadIdx.x;  // 4g*4w*4G*8ks*64lane = 32768
  if (idx >= 32768) return;
  int lane = idx & 63, ks = (idx >> 6) & 7, G = (idx >> 9) & 3;
  int w = (idx >> 11) & 3, g = (idx >> 13) & 3;
  int ncol = G * 256 + g * 64 + 16 * w + (lane & 15);
  int kb = ks * 32 + ((lane >> 4) << 3);
  union { unsigned short s[8]; uint4 v; } u;
  #pragma unroll
  for (int e = 0; e < 8; ++e) u.s[e] = f2bf(rk[(size_t)(kb + e) * 1024 + ncol]);
  ((uint4*)wf)[idx] = u.v;
}

// ---- xw = x @ kernel ; BM=BN=128, BK=32, 256 thr, B split hi+lo (2 MFMAs) ----
__global__ __launch_bounds__(256, 2) void gemm_xw(
    const float* __restrict__ x, const unsigned short* __restrict__ wt_hi,
    const unsigned short* __restrict__ wt_lo, __half* __restrict__ xw) {
  __shared__ __align__(16) unsigned short As[128][40];
  __shared__ __align__(16) unsigned short Bh[128][40];
  __shared__ __align__(16) unsigned short Bl[128][40];
  const int tid = threadIdx.x;
  const int m0 = blockIdx.y << 7;
  const int n0 = blockIdx.x << 7;
  const int lane = tid & 63, wv = tid >> 6;
  const int wr = wv >> 1, wc = wv & 1;
  const int fm = lane & 15;
  const int fkb = (lane >> 4) << 3;
  const int sr = tid >> 1, sh = (tid & 1) << 4;
  f32x4 acc[4][4];
  #pragma unroll
  for (int a = 0; a < 4; ++a)
    #pragma unroll
    for (int b = 0; b < 4; ++b) acc[a][b] = (f32x4){0.f, 0.f, 0.f, 0.f};

  const float* xsrc = x + (size_t)(m0 + sr) * 784;
  const unsigned short* bhsrc = wt_hi + (size_t)(n0 + sr) * 800;
  const unsigned short* blsrc = wt_lo + (size_t)(n0 + sr) * 800;

  for (int kt = 0; kt < 25; ++kt) {
    const int kb = (kt << 5) + sh;
    float va[16];
    if (kb + 16 <= 784) {
      const float4* s = (const float4*)(xsrc + kb);
      #pragma unroll
      for (int q = 0; q < 4; ++q) {
        float4 f = s[q];
        va[q * 4 + 0] = f.x; va[q * 4 + 1] = f.y;
        va[q * 4 + 2] = f.z; va[q * 4 + 3] = f.w;
      }
    } else {
      #pragma unroll
      for (int q = 0; q < 16; ++q) va[q] = 0.f;
    }
    uint32_t pk[8];
    #pragma unroll
    for (int q = 0; q < 8; ++q)
      pk[q] = (uint32_t)f2bf(va[2 * q]) | ((uint32_t)f2bf(va[2 * q + 1]) << 16);
    uint4* adst = (uint4*)&As[sr][sh];
    adst[0] = make_uint4(pk[0], pk[1], pk[2], pk[3]);
    adst[1] = make_uint4(pk[4], pk[5], pk[6], pk[7]);
    const uint4* bh4 = (const uint4*)(bhsrc + kb);
    const uint4* bl4 = (const uint4*)(blsrc + kb);
    uint4* bhd = (uint4*)&Bh[sr][sh];
    uint4* bld = (uint4*)&Bl[sr][sh];
    bhd[0] = bh4[0]; bhd[1] = bh4[1];
    bld[0] = bl4[0]; bld[1] = bl4[1];
    __syncthreads();

    short8 af[4], bh[4], bl[4];
    #pragma unroll
    for (int mt = 0; mt < 4; ++mt)
      af[mt] = *(const short8*)&As[(wr << 6) + (mt << 4) + fm][fkb];
    #pragma unroll
    for (int nt = 0; nt < 4; ++nt) {
      bh[nt] = *(const short8*)&Bh[(wc << 6) + (nt << 4) + fm][fkb];
      bl[nt] = *(const short8*)&Bl[(wc << 6) + (nt << 4) + fm][fkb];
    }
    #pragma unroll
    for (int mt = 0; mt < 4; ++mt)
      #pragma unroll
      for (int nt = 0; nt < 4; ++nt) {
        acc[mt][nt] = __builtin_amdgcn_mfma_f32_16x16x32_bf16(af[mt], bh[nt], acc[mt][nt], 0, 0, 0);
        acc[mt][nt] = __builtin_amdgcn_mfma_f32_16x16x32_bf16(af[mt], bl[nt], acc[mt][nt], 0, 0, 0);
      }
    __syncthreads();
  }
  const int rbase = (lane >> 4) << 2;
  #pragma unroll
  for (int mt = 0; mt < 4; ++mt)
    #pragma unroll
    for (int nt = 0; nt < 4; ++nt) {
      int col = n0 + (wc << 6) + (nt << 4) + fm;
      #pragma unroll
      for (int r = 0; r < 4; ++r) {
        int row = m0 + (wr << 6) + (mt << 4) + rbase + r;
        xw[(size_t)row * 1024 + col] = __float2half(acc[mt][nt][r]);
      }
    }
}

// ---- persistent recurrent scan: R4 exchange + LDS weights + raw barriers ----
__global__ __launch_bounds__(256, 1) void scan_kernel(
    const unsigned short* __restrict__ wf, __half* __restrict__ xw,
    unsigned long long* __restrict__ pub,
    const float* __restrict__ bias, const float* __restrict__ wci,
    const float* __restrict__ wcf, const float* __restrict__ wco,
    const float* __restrict__ gamma, const float* __restrict__ beta,
    const float* __restrict__ mean, const float* __restrict__ var) {
  __shared__ __align__(16) unsigned short h_all[16][264];
  __shared__ __align__(16) uint4 wlds[8192];  // 128 KB: Wr slice, (w,G,ks,lane) frags
  const int tid = threadIdx.x, lane = tid & 63, w = tid >> 6;
  const int gr = blockIdx.x & 7;   // batch-group (same XCD via %8 round-robin)
  const int g = blockIdx.x >> 3;   // member: owns jj in [0,64) -> jg = 64g+jj
  const int c = lane & 15, q = lane >> 4;
  const int jj = 16 * w + c, jg = 64 * g + jj;

  // stage this WG's Wr slice into LDS once (layout preserved from repack_wf)
  {
    const uint4* src = (const uint4*)wf + (size_t)g * 8192;
    for (int i = tid; i < 8192; i += 256) wlds[i] = src[i];
  }
  const short8* wl8 = (const short8*)wlds;

  const float b0 = bias[jg], b1 = bias[256 + jg], b2 = bias[512 + jg], b3 = bias[768 + jg];
  const float pci = wci[jg], pcf = wcf[jg], pco = wco[jg];
  const float bna = gamma[jg] * rsqrtf(var[jg] + 1e-3f);
  const float bnb = beta[jg] - mean[jg] * bna;
  float c2[4] = {0.f, 0.f, 0.f, 0.f};

  unsigned long long* mypub = pub + (size_t)(gr * 4 + g) * 512 + jj * 8 + q * 2;
  // zero own words (both parities): no garbage-tag collisions from wt_hi overlay
  __hip_atomic_store(mypub + 0, 0ull, __ATOMIC_RELAXED, __HIP_MEMORY_SCOPE_AGENT);
  __hip_atomic_store(mypub + 1, 0ull, __ATOMIC_RELAXED, __HIP_MEMORY_SCOPE_AGENT);
  __hip_atomic_store(mypub + 16384, 0ull, __ATOMIC_RELAXED, __HIP_MEMORY_SCOPE_AGENT);
  __hip_atomic_store(mypub + 16385, 0ull, __ATOMIC_RELAXED, __HIP_MEMORY_SCOPE_AGENT);

  const size_t xbase = ((size_t)(gr * 16 + 4 * q) << 9);  // row of batch 4q, t=0

  // prefetch xw for s=0
  float xp[4][4];
  #pragma unroll
  for (int G = 0; G < 4; ++G)
    #pragma unroll
    for (int r = 0; r < 4; ++r)
      xp[G][r] = __half2float(xw[((xbase + ((size_t)r << 9)) << 10) + G * 256 + jg]);

  __syncthreads();  // wlds staged (once; full sync fine here)

  for (int s = 0; s < 512; ++s) {
    f32x4 acc[4];
    #pragma unroll
    for (int G = 0; G < 4; ++G) acc[G] = (f32x4){0.f, 0.f, 0.f, 0.f};

    if (s > 0) {
      // poll peers' tagged h(s) words (relaxed, agent scope — no fences)
      unsigned long long vv[6];
      unsigned need = 63u;
      long cnt = 0;
      const size_t slot = (size_t)(s & 1) * 16384;
      while (need) {
        #pragma unroll
        for (int pp = 0; pp < 3; ++pp) {
          int p = (g + 1 + pp) & 3;
          #pragma unroll
          for (int u2 = 0; u2 < 2; ++u2) {
            int bit = pp * 2 + u2;
            if (need & (1u << bit)) {
              unsigned long long v = __hip_atomic_load(
                  pub + slot + (size_t)(gr * 4 + p) * 512 + 2 * tid + u2,
                  __ATOMIC_RELAXED, __HIP_MEMORY_SCOPE_AGENT);
              if ((unsigned)(v >> 32) == (unsigned)s) {
                vv[bit] = v;
                need &= ~(1u << bit);
              }
            }
          }
        }
        if (++cnt > (1L << 22)) break;  // bounded: no infinite hang
      }
      // stage peer h into h_all
      #pragma unroll
      for (int pp = 0; pp < 3; ++pp) {
        int p = (g + 1 + pp) & 3;
        #pragma unroll
        for (int u2 = 0; u2 < 2; ++u2) {
          int wid = 2 * tid + u2;
          unsigned long long v = vv[pp * 2 + u2];
          int jj2 = wid >> 3, qq = (wid >> 1) & 3, uu = wid & 1;
          int m0 = 4 * qq + 2 * uu, col = 64 * p + jj2;
          h_all[m0][col] = (unsigned short)(v & 0xffffu);
          h_all[m0 + 1][col] = (unsigned short)((v >> 16) & 0xffffu);
        }
      }
      bar_raw();  // BAR-A: peer h visible (LDS only; vmem stays in flight)
      // z_rec = h(s) @ WrSlice — B-frags streamed from LDS (conflict-free b128)
      #pragma unroll
      for (int ks = 0; ks < 8; ++ks) {
        short8 afk = *(const short8*)&h_all[c][ks * 32 + q * 8];
        #pragma unroll
        for (int G = 0; G < 4; ++G) {
          short8 bfr = wl8[((w * 4 + G) * 8 + ks) * 64 + lane];
          acc[G] = __builtin_amdgcn_mfma_f32_16x16x32_bf16(afk, bfr, acc[G], 0, 0, 0);
        }
      }
      bar_raw();  // BAR-B: h_all reads done before overwrite below
    }

    // gates, directly in C-layout: lane owns (jj, batches 4q..4q+3)
    float hn[4];
    #pragma unroll
    for (int r = 0; r < 4; ++r) {
      float z0 = acc[0][r] + b0 + xp[0][r];
      float z1 = acc[1][r] + b1 + xp[1][r];
      float z2 = acc[2][r] + b2 + xp[2][r];
      float z3 = acc[3][r] + b3 + xp[3][r];
      float ig = sigm(z0 + c2[r] * pci);
      float fg = sigm(z1 + c2[r] * pcf);
      float cn = fg * c2[r] + ig * tanh_(z2);
      float og = sigm(z3 + cn * pco);
      float h = og * tanh_(cn);
      c2[r] = cn;
      hn[r] = h;
      if ((r & 1) && s < 511) {  // publish pair ASAP: overlaps remaining gates
        unsigned long long pv =
            ((unsigned long long)(unsigned)(s + 1) << 32) |
            (unsigned long long)(((uint32_t)f2bf(hn[r - 1])) |
                                 ((uint32_t)f2bf(hn[r]) << 16));
        __hip_atomic_store(mypub + (size_t)((s + 1) & 1) * 16384 + (r >> 1), pv,
                           __ATOMIC_RELAXED, __HIP_MEMORY_SCOPE_AGENT);
      }
    }
    #pragma unroll
    for (int r = 0; r < 4; ++r) h_all[4 * q + r][jg] = f2bf(hn[r]);
    // y = tanh(BN(h)) -> xw col jg (final FC reads later)
    #pragma unroll
    for (int r = 0; r < 4; ++r) {
      float y = tanh_(hn[r] * bna + bnb);
      xw[((xbase + ((size_t)r << 9) + s) << 10) + jg] = __float2half(y);
    }
    // prefetch xw for s+1 (latency hidden under next poll/MFMA; no drain now)
    if (s < 511) {
      #pragma unroll
      for (int G = 0; G < 4; ++G)
        #pragma unroll
        for (int r = 0; r < 4; ++r)
          xp[G][r] = __half2float(
              xw[((xbase + ((size_t)r << 9) + (s + 1)) << 10) + G * 256 + jg]);
    }
  }
}

// ---- final FC: out[b,t,c] = sum_j y[b,t,j] * fcw[j,c]; wave per row ----
__global__ __launch_bounds__(256) void final_fc(const __half* __restrict__ xw,
                                                const float* __restrict__ fcw,
                                                float* __restrict__ out) {
  const int tid = threadIdx.x, lane = tid & 63, w = tid >> 6;
  const int wid = blockIdx.x * 4 + w;  // 512 waves
  float fw[4][10];
  #pragma unroll
  for (int q = 0; q < 4; ++q)
    #pragma unroll
    for (int c = 0; c < 10; ++c) fw[q][c] = fcw[(lane * 4 + q) * 10 + c];
  for (int it = 0; it < 128; ++it) {
    const int row = it * 512 + wid;
    uint2 u = *(const uint2*)(xw + ((size_t)row << 10) + lane * 4);
    const __half* hp = (const __half*)&u;
    float y0 = __half2float(hp[0]), y1 = __half2float(hp[1]);
    float y2 = __half2float(hp[2]), y3 = __half2float(hp[3]);
    float p[10];
    #pragma unroll
    for (int c = 0; c < 10; ++c)
      p[c] = y0 * fw[0][c] + y1 * fw[1][c] + y2 * fw[2][c] + y3 * fw[3][c];
    #pragma unroll
    for (int off = 1; off < 64; off <<= 1)
      #pragma unroll
      for (int c = 0; c < 10; ++c) p[c] += __shfl_xor(p[c], off, 64);
    if (lane == 0) {
      #pragma unroll
      for (int c = 0; c < 10; ++c) out[(size_t)row * 10 + c] = p[c];
    }
  }
}

extern "C" void kernel_launch(void* const* d_in, const int* in_sizes, int n_in,
                              void* d_out, int out_size, void* d_ws, size_t ws_size,
                              hipStream_t stream) {
  const float* x     = (const float*)d_in[0];
  const float* kw    = (const float*)d_in[1];
  const float* rk    = (const float*)d_in[2];
  const float* bias  = (const float*)d_in[3];
  const float* wci   = (const float*)d_in[4];
  const float* wcf   = (const float*)d_in[5];
  const float* wco   = (const float*)d_in[6];
  const float* gamma = (const float*)d_in[7];
  const float* beta  = (const float*)d_in[8];
  const float* mean  = (const float*)d_in[9];
  const float* var   = (const float*)d_in[10];
  const float* fcw   = (const float*)d_in[11];
  float* out = (float*)d_out;

  char* ws = (char*)d_ws;
  __half*         xw    = (__half*)ws;                                 // 134217728 B
  unsigned short* wt_hi = (unsigned short*)(ws + 134217728);           // 1638400 B
  unsigned short* wt_lo = (unsigned short*)(ws + 134217728 + 1638400); // 1638400 B
  unsigned short* wfrag = (unsigned short*)(ws + 134217728 + 3276800); // 524288 B
  // pub overlays wt_hi (dead after gemm_xw): 2 parity * 32 WG * 512 u64 = 262144 B
  unsigned long long* pub = (unsigned long long*)(ws + 134217728);

  repack_w<<<dim3((1024 * 800 + 255) / 256), dim3(256), 0, stream>>>(kw, wt_hi, wt_lo);
  repack_wf<<<dim3(128), dim3(256), 0, stream>>>(rk, wfrag);
  gemm_xw<<<dim3(8, 512), dim3(256), 0, stream>>>(x, wt_hi, wt_lo, xw);
  scan_kernel<<<dim3(32), dim3(256), 0, stream>>>(wfrag, xw, pub, bias,
                                                  wci, wcf, wco, gamma, beta, mean, var);
  final_fc<<<dim3(128), dim3(256), 0, stream>>>(xw, fcw, out);
}

// Round 14
// 2249.866 us; speedup vs baseline: 2.5838x; 1.0001x over previous
//
#include <hip/hip_runtime.h>
#include <hip/hip_bf16.h>
#include <hip/hip_fp16.h>
#include <stdint.h>

// LSTMModelLite: B=128,T=512,F=784,H=256,C=10
// R8 = R7 + SYSTEM-scope (coherent) publish/poll.
//   R7 counters isolated the wall: publish->peer-visibility ~6400cyc. The
//   agent-scope relaxed store dirty-caches in the producer's private L2;
//   group members are evidently NOT same-XCD (the %8 assumption fails),
//   so peers only see the value after writeback. Fix: relaxed SYSTEM-scope
//   store/load = per-access sc0+sc1 write-through/bypass to the coherent
//   memory side (L3). No fences -> no buffer_wb/inv storms.
//   Everything else identical to R7 (LDS weights, raw barriers, rcp gates).
// ws: xw 134217728 | pub 262144 (overlay wt_hi, dead after gemm) |
//     wt_lo 1638400 | wfrag 524288

typedef __attribute__((ext_vector_type(8))) short short8;
typedef __attribute__((ext_vector_type(4))) float f32x4;

__device__ __forceinline__ unsigned short f2bf(float f) {
  union { float f; uint32_t u; } v; v.f = f;
  return (unsigned short)((v.u + 0x7fffu + ((v.u >> 16) & 1u)) >> 16);
}
__device__ __forceinline__ float bfu2f(uint32_t u16) {
  union { uint32_t u; float f; } v; v.u = u16 << 16; return v.f;
}
__device__ __forceinline__ float sigm(float x) {
  return __builtin_amdgcn_rcpf(1.f + __expf(-x));
}
__device__ __forceinline__ float tanh_(float x) {
  float e = __expf(2.f * x);
  return 1.f - 2.f * __builtin_amdgcn_rcpf(e + 1.f);
}
// raw barrier: waits LDS ops only; vmem (y stores, xw prefetch, pub) stays
// in flight across it. memory-clobber sandwich pins compiler ordering.
__device__ __forceinline__ void bar_raw() {
  asm volatile("s_waitcnt lgkmcnt(0)" ::: "memory");
  __builtin_amdgcn_s_barrier();
  asm volatile("" ::: "memory");
}

__global__ void repack_w(const float* __restrict__ w, unsigned short* __restrict__ wt_hi,
                         unsigned short* __restrict__ wt_lo) {
  int idx = blockIdx.x * 256 + threadIdx.x;  // n*800 + k
  if (idx >= 1024 * 800) return;
  int n = idx / 800, k = idx - n * 800;
  float v = (k < 784) ? w[k * 1024 + n] : 0.f;
  unsigned short hi = f2bf(v);
  wt_hi[idx] = hi;
  wt_lo[idx] = f2bf(v - bfu2f(hi));
}

// rec_kernel fp32 [256 k][1024 n] -> B-frags indexed (g,w,G,ks,lane,8)
// g in [0,4): WG; w in [0,4): wave   (R4 layout, verbatim)
__global__ void repack_wf(const float* __restrict__ rk, unsigned short* __restrict__ wf) {
  int idx = blockIdx.x * 256 + threadIdx.x;  // 4g*4w*4G*8ks*64lane = 32768
  if (idx >= 32768) return;
  int lane = idx & 63, ks = (idx >> 6) & 7, G = (idx >> 9) & 3;
  int w = (idx >> 11) & 3, g = (idx >> 13) & 3;
  int ncol = G * 256 + g * 64 + 16 * w + (lane & 15);
  int kb = ks * 32 + ((lane >> 4) << 3);
  union { unsigned short s[8]; uint4 v; } u;
  #pragma unroll
  for (int e = 0; e < 8; ++e) u.s[e] = f2bf(rk[(size_t)(kb + e) * 1024 + ncol]);
  ((uint4*)wf)[idx] = u.v;
}

// ---- xw = x @ kernel ; BM=BN=128, BK=32, 256 thr, B split hi+lo (2 MFMAs) ----
__global__ __launch_bounds__(256, 2) void gemm_xw(
    const float* __restrict__ x, const unsigned short* __restrict__ wt_hi,
    const unsigned short* __restrict__ wt_lo, __half* __restrict__ xw) {
  __shared__ __align__(16) unsigned short As[128][40];
  __shared__ __align__(16) unsigned short Bh[128][40];
  __shared__ __align__(16) unsigned short Bl[128][40];
  const int tid = threadIdx.x;
  const int m0 = blockIdx.y << 7;
  const int n0 = blockIdx.x << 7;
  const int lane = tid & 63, wv = tid >> 6;
  const int wr = wv >> 1, wc = wv & 1;
  const int fm = lane & 15;
  const int fkb = (lane >> 4) << 3;
  const int sr = tid >> 1, sh = (tid & 1) << 4;
  f32x4 acc[4][4];
  #pragma unroll
  for (int a = 0; a < 4; ++a)
    #pragma unroll
    for (int b = 0; b < 4; ++b) acc[a][b] = (f32x4){0.f, 0.f, 0.f, 0.f};

  const float* xsrc = x + (size_t)(m0 + sr) * 784;
  const unsigned short* bhsrc = wt_hi + (size_t)(n0 + sr) * 800;
  const unsigned short* blsrc = wt_lo + (size_t)(n0 + sr) * 800;

  for (int kt = 0; kt < 25; ++kt) {
    const int kb = (kt << 5) + sh;
    float va[16];
    if (kb + 16 <= 784) {
      const float4* s = (const float4*)(xsrc + kb);
      #pragma unroll
      for (int q = 0; q < 4; ++q) {
        float4 f = s[q];
        va[q * 4 + 0] = f.x; va[q * 4 + 1] = f.y;
        va[q * 4 + 2] = f.z; va[q * 4 + 3] = f.w;
      }
    } else {
      #pragma unroll
      for (int q = 0; q < 16; ++q) va[q] = 0.f;
    }
    uint32_t pk[8];
    #pragma unroll
    for (int q = 0; q < 8; ++q)
      pk[q] = (uint32_t)f2bf(va[2 * q]) | ((uint32_t)f2bf(va[2 * q + 1]) << 16);
    uint4* adst = (uint4*)&As[sr][sh];
    adst[0] = make_uint4(pk[0], pk[1], pk[2], pk[3]);
    adst[1] = make_uint4(pk[4], pk[5], pk[6], pk[7]);
    const uint4* bh4 = (const uint4*)(bhsrc + kb);
    const uint4* bl4 = (const uint4*)(blsrc + kb);
    uint4* bhd = (uint4*)&Bh[sr][sh];
    uint4* bld = (uint4*)&Bl[sr][sh];
    bhd[0] = bh4[0]; bhd[1] = bh4[1];
    bld[0] = bl4[0]; bld[1] = bl4[1];
    __syncthreads();

    short8 af[4], bh[4], bl[4];
    #pragma unroll
    for (int mt = 0; mt < 4; ++mt)
      af[mt] = *(const short8*)&As[(wr << 6) + (mt << 4) + fm][fkb];
    #pragma unroll
    for (int nt = 0; nt < 4; ++nt) {
      bh[nt] = *(const short8*)&Bh[(wc << 6) + (nt << 4) + fm][fkb];
      bl[nt] = *(const short8*)&Bl[(wc << 6) + (nt << 4) + fm][fkb];
    }
    #pragma unroll
    for (int mt = 0; mt < 4; ++mt)
      #pragma unroll
      for (int nt = 0; nt < 4; ++nt) {
        acc[mt][nt] = __builtin_amdgcn_mfma_f32_16x16x32_bf16(af[mt], bh[nt], acc[mt][nt], 0, 0, 0);
        acc[mt][nt] = __builtin_amdgcn_mfma_f32_16x16x32_bf16(af[mt], bl[nt], acc[mt][nt], 0, 0, 0);
      }
    __syncthreads();
  }
  const int rbase = (lane >> 4) << 2;
  #pragma unroll
  for (int mt = 0; mt < 4; ++mt)
    #pragma unroll
    for (int nt = 0; nt < 4; ++nt) {
      int col = n0 + (wc << 6) + (nt << 4) + fm;
      #pragma unroll
      for (int r = 0; r < 4; ++r) {
        int row = m0 + (wr << 6) + (mt << 4) + rbase + r;
        xw[(size_t)row * 1024 + col] = __float2half(acc[mt][nt][r]);
      }
    }
}

// ---- persistent recurrent scan: LDS weights + SYSTEM-scope exchange ----
__global__ __launch_bounds__(256, 1) void scan_kernel(
    const unsigned short* __restrict__ wf, __half* __restrict__ xw,
    unsigned long long* __restrict__ pub,
    const float* __restrict__ bias, const float* __restrict__ wci,
    const float* __restrict__ wcf, const float* __restrict__ wco,
    const float* __restrict__ gamma, const float* __restrict__ beta,
    const float* __restrict__ mean, const float* __restrict__ var) {
  __shared__ __align__(16) unsigned short h_all[16][264];
  __shared__ __align__(16) uint4 wlds[8192];  // 128 KB: Wr slice, (w,G,ks,lane) frags
  const int tid = threadIdx.x, lane = tid & 63, w = tid >> 6;
  const int gr = blockIdx.x & 7;   // batch-group
  const int g = blockIdx.x >> 3;   // member: owns jj in [0,64) -> jg = 64g+jj
  const int c = lane & 15, q = lane >> 4;
  const int jj = 16 * w + c, jg = 64 * g + jj;

  // stage this WG's Wr slice into LDS once (layout preserved from repack_wf)
  {
    const uint4* src = (const uint4*)wf + (size_t)g * 8192;
    for (int i = tid; i < 8192; i += 256) wlds[i] = src[i];
  }
  const short8* wl8 = (const short8*)wlds;

  const float b0 = bias[jg], b1 = bias[256 + jg], b2 = bias[512 + jg], b3 = bias[768 + jg];
  const float pci = wci[jg], pcf = wcf[jg], pco = wco[jg];
  const float bna = gamma[jg] * rsqrtf(var[jg] + 1e-3f);
  const float bnb = beta[jg] - mean[jg] * bna;
  float c2[4] = {0.f, 0.f, 0.f, 0.f};

  unsigned long long* mypub = pub + (size_t)(gr * 4 + g) * 512 + jj * 8 + q * 2;
  // zero own words (both parities): no garbage-tag collisions from wt_hi overlay
  __hip_atomic_store(mypub + 0, 0ull, __ATOMIC_RELAXED, __HIP_MEMORY_SCOPE_SYSTEM);
  __hip_atomic_store(mypub + 1, 0ull, __ATOMIC_RELAXED, __HIP_MEMORY_SCOPE_SYSTEM);
  __hip_atomic_store(mypub + 16384, 0ull, __ATOMIC_RELAXED, __HIP_MEMORY_SCOPE_SYSTEM);
  __hip_atomic_store(mypub + 16385, 0ull, __ATOMIC_RELAXED, __HIP_MEMORY_SCOPE_SYSTEM);

  const size_t xbase = ((size_t)(gr * 16 + 4 * q) << 9);  // row of batch 4q, t=0

  // prefetch xw for s=0
  float xp[4][4];
  #pragma unroll
  for (int G = 0; G < 4; ++G)
    #pragma unroll
    for (int r = 0; r < 4; ++r)
      xp[G][r] = __half2float(xw[((xbase + ((size_t)r << 9)) << 10) + G * 256 + jg]);

  __syncthreads();  // wlds staged (once; full sync fine here)

  for (int s = 0; s < 512; ++s) {
    f32x4 acc[4];
    #pragma unroll
    for (int G = 0; G < 4; ++G) acc[G] = (f32x4){0.f, 0.f, 0.f, 0.f};

    if (s > 0) {
      // poll peers' tagged h(s) words (relaxed SYSTEM scope: coherent, no fences)
      unsigned long long vv[6];
      unsigned need = 63u;
      long cnt = 0;
      const size_t slot = (size_t)(s & 1) * 16384;
      while (need) {
        #pragma unroll
        for (int pp = 0; pp < 3; ++pp) {
          int p = (g + 1 + pp) & 3;
          #pragma unroll
          for (int u2 = 0; u2 < 2; ++u2) {
            int bit = pp * 2 + u2;
            if (need & (1u << bit)) {
              unsigned long long v = __hip_atomic_load(
                  pub + slot + (size_t)(gr * 4 + p) * 512 + 2 * tid + u2,
                  __ATOMIC_RELAXED, __HIP_MEMORY_SCOPE_SYSTEM);
              if ((unsigned)(v >> 32) == (unsigned)s) {
                vv[bit] = v;
                need &= ~(1u << bit);
              }
            }
          }
        }
        if (++cnt > (1L << 22)) break;  // bounded: no infinite hang
      }
      // stage peer h into h_all
      #pragma unroll
      for (int pp = 0; pp < 3; ++pp) {
        int p = (g + 1 + pp) & 3;
        #pragma unroll
        for (int u2 = 0; u2 < 2; ++u2) {
          int wid = 2 * tid + u2;
          unsigned long long v = vv[pp * 2 + u2];
          int jj2 = wid >> 3, qq = (wid >> 1) & 3, uu = wid & 1;
          int m0 = 4 * qq + 2 * uu, col = 64 * p + jj2;
          h_all[m0][col] = (unsigned short)(v & 0xffffu);
          h_all[m0 + 1][col] = (unsigned short)((v >> 16) & 0xffffu);
        }
      }
      bar_raw();  // BAR-A: peer h visible (LDS only; vmem stays in flight)
      // z_rec = h(s) @ WrSlice — B-frags streamed from LDS (conflict-free b128)
      #pragma unroll
      for (int ks = 0; ks < 8; ++ks) {
        short8 afk = *(const short8*)&h_all[c][ks * 32 + q * 8];
        #pragma unroll
        for (int G = 0; G < 4; ++G) {
          short8 bfr = wl8[((w * 4 + G) * 8 + ks) * 64 + lane];
          acc[G] = __builtin_amdgcn_mfma_f32_16x16x32_bf16(afk, bfr, acc[G], 0, 0, 0);
        }
      }
      bar_raw();  // BAR-B: h_all reads done before overwrite below
    }

    // gates, directly in C-layout: lane owns (jj, batches 4q..4q+3)
    float hn[4];
    #pragma unroll
    for (int r = 0; r < 4; ++r) {
      float z0 = acc[0][r] + b0 + xp[0][r];
      float z1 = acc[1][r] + b1 + xp[1][r];
      float z2 = acc[2][r] + b2 + xp[2][r];
      float z3 = acc[3][r] + b3 + xp[3][r];
      float ig = sigm(z0 + c2[r] * pci);
      float fg = sigm(z1 + c2[r] * pcf);
      float cn = fg * c2[r] + ig * tanh_(z2);
      float og = sigm(z3 + cn * pco);
      float h = og * tanh_(cn);
      c2[r] = cn;
      hn[r] = h;
      if ((r & 1) && s < 511) {  // publish pair ASAP: overlaps remaining gates
        unsigned long long pv =
            ((unsigned long long)(unsigned)(s + 1) << 32) |
            (unsigned long long)(((uint32_t)f2bf(hn[r - 1])) |
                                 ((uint32_t)f2bf(hn[r]) << 16));
        __hip_atomic_store(mypub + (size_t)((s + 1) & 1) * 16384 + (r >> 1), pv,
                           __ATOMIC_RELAXED, __HIP_MEMORY_SCOPE_SYSTEM);
      }
    }
    #pragma unroll
    for (int r = 0; r < 4; ++r) h_all[4 * q + r][jg] = f2bf(hn[r]);
    // y = tanh(BN(h)) -> xw col jg (final FC reads later)
    #pragma unroll
    for (int r = 0; r < 4; ++r) {
      float y = tanh_(hn[r] * bna + bnb);
      xw[((xbase + ((size_t)r << 9) + s) << 10) + jg] = __float2half(y);
    }
    // prefetch xw for s+1 (latency hidden under next poll/MFMA; no drain now)
    if (s < 511) {
      #pragma unroll
      for (int G = 0; G < 4; ++G)
        #pragma unroll
        for (int r = 0; r < 4; ++r)
          xp[G][r] = __half2float(
              xw[((xbase + ((size_t)r << 9) + (s + 1)) << 10) + G * 256 + jg]);
    }
  }
}

// ---- final FC: out[b,t,c] = sum_j y[b,t,j] * fcw[j,c]; wave per row ----
__global__ __launch_bounds__(256) void final_fc(const __half* __restrict__ xw,
                                                const float* __restrict__ fcw,
                                                float* __restrict__ out) {
  const int tid = threadIdx.x, lane = tid & 63, w = tid >> 6;
  const int wid = blockIdx.x * 4 + w;  // 512 waves
  float fw[4][10];
  #pragma unroll
  for (int q = 0; q < 4; ++q)
    #pragma unroll
    for (int c = 0; c < 10; ++c) fw[q][c] = fcw[(lane * 4 + q) * 10 + c];
  for (int it = 0; it < 128; ++it) {
    const int row = it * 512 + wid;
    uint2 u = *(const uint2*)(xw + ((size_t)row << 10) + lane * 4);
    const __half* hp = (const __half*)&u;
    float y0 = __half2float(hp[0]), y1 = __half2float(hp[1]);
    float y2 = __half2float(hp[2]), y3 = __half2float(hp[3]);
    float p[10];
    #pragma unroll
    for (int c = 0; c < 10; ++c)
      p[c] = y0 * fw[0][c] + y1 * fw[1][c] + y2 * fw[2][c] + y3 * fw[3][c];
    #pragma unroll
    for (int off = 1; off < 64; off <<= 1)
      #pragma unroll
      for (int c = 0; c < 10; ++c) p[c] += __shfl_xor(p[c], off, 64);
    if (lane == 0) {
      #pragma unroll
      for (int c = 0; c < 10; ++c) out[(size_t)row * 10 + c] = p[c];
    }
  }
}

extern "C" void kernel_launch(void* const* d_in, const int* in_sizes, int n_in,
                              void* d_out, int out_size, void* d_ws, size_t ws_size,
                              hipStream_t stream) {
  const float* x     = (const float*)d_in[0];
  const float* kw    = (const float*)d_in[1];
  const float* rk    = (const float*)d_in[2];
  const float* bias  = (const float*)d_in[3];
  const float* wci   = (const float*)d_in[4];
  const float* wcf   = (const float*)d_in[5];
  const float* wco   = (const float*)d_in[6];
  const float* gamma = (const float*)d_in[7];
  const float* beta  = (const float*)d_in[8];
  const float* mean  = (const float*)d_in[9];
  const float* var   = (const float*)d_in[10];
  const float* fcw   = (const float*)d_in[11];
  float* out = (float*)d_out;

  char* ws = (char*)d_ws;
  __half*         xw    = (__half*)ws;                                 // 134217728 B
  unsigned short* wt_hi = (unsigned short*)(ws + 134217728);           // 1638400 B
  unsigned short* wt_lo = (unsigned short*)(ws + 134217728 + 1638400); // 1638400 B
  unsigned short* wfrag = (unsigned short*)(ws + 134217728 + 3276800); // 524288 B
  // pub overlays wt_hi (dead after gemm_xw): 2 parity * 32 WG * 512 u64 = 262144 B
  unsigned long long* pub = (unsigned long long*)(ws + 134217728);

  repack_w<<<dim3((1024 * 800 + 255) / 256), dim3(256), 0, stream>>>(kw, wt_hi, wt_lo);
  repack_wf<<<dim3(128), dim3(256), 0, stream>>>(rk, wfrag);
  gemm_xw<<<dim3(8, 512), dim3(256), 0, stream>>>(x, wt_hi, wt_lo, xw);
  scan_kernel<<<dim3(32), dim3(256), 0, stream>>>(wfrag, xw, pub, bias,
                                                  wci, wcf, wco, gamma, beta, mean, var);
  final_fc<<<dim3(128), dim3(256), 0, stream>>>(xw, fcw, out);
}

// Round 16
// 1933.052 us; speedup vs baseline: 3.0073x; 1.1639x over previous
//
#include <hip/hip_runtime.h>
#include <hip/hip_bf16.h>
#include <hip/hip_fp16.h>
#include <stdint.h>

// LSTMModelLite: B=128,T=512,F=784,H=256,C=10
// R10 = R8 + BATCHED POLL (single-variable change; R9's sc0 L2-path reverted
//   — it failed visibility, absmax 0.226).
//   New model from R7/R8/R9 evidence: the 7400cyc/step wall is POLL
//   SERIALIZATION — R4-R8's branchy per-bit conditional loads forced
//   load->waitcnt->check x6 serially (~6 uncached round trips ~4200cyc per
//   poll iteration). Fix: 6 UNCONDITIONAL relaxed atomic loads issued
//   back-to-back (compiler clusters them under one s_waitcnt), then a
//   combined tag check. Exchange path itself = R8's proven SYSTEM-scope
//   relaxed atomics (correct on all placements). Cap back to 1<<22.
//   Everything else identical to R8 (LDS weights, raw barriers, rcp gates,
//   32 WGs = 8 groups x 4, parity dbuf, tag-embedded words).
// ws: xw 134217728 | pub 262144 (overlay wt_hi, dead after gemm) |
//     wt_lo 1638400 | wfrag 524288

typedef __attribute__((ext_vector_type(8))) short short8;
typedef __attribute__((ext_vector_type(4))) float f32x4;

__device__ __forceinline__ unsigned short f2bf(float f) {
  union { float f; uint32_t u; } v; v.f = f;
  return (unsigned short)((v.u + 0x7fffu + ((v.u >> 16) & 1u)) >> 16);
}
__device__ __forceinline__ float bfu2f(uint32_t u16) {
  union { uint32_t u; float f; } v; v.u = u16 << 16; return v.f;
}
__device__ __forceinline__ float sigm(float x) {
  return __builtin_amdgcn_rcpf(1.f + __expf(-x));
}
__device__ __forceinline__ float tanh_(float x) {
  float e = __expf(2.f * x);
  return 1.f - 2.f * __builtin_amdgcn_rcpf(e + 1.f);
}
// raw barrier: waits LDS ops only; vmem (y stores, xw prefetch, pub) stays
// in flight across it. memory-clobber sandwich pins compiler ordering.
__device__ __forceinline__ void bar_raw() {
  asm volatile("s_waitcnt lgkmcnt(0)" ::: "memory");
  __builtin_amdgcn_s_barrier();
  asm volatile("" ::: "memory");
}

__global__ void repack_w(const float* __restrict__ w, unsigned short* __restrict__ wt_hi,
                         unsigned short* __restrict__ wt_lo) {
  int idx = blockIdx.x * 256 + threadIdx.x;  // n*800 + k
  if (idx >= 1024 * 800) return;
  int n = idx / 800, k = idx - n * 800;
  float v = (k < 784) ? w[k * 1024 + n] : 0.f;
  unsigned short hi = f2bf(v);
  wt_hi[idx] = hi;
  wt_lo[idx] = f2bf(v - bfu2f(hi));
}

// rec_kernel fp32 [256 k][1024 n] -> B-frags indexed (g,w,G,ks,lane,8)
// g in [0,4): WG; w in [0,4): wave   (R4 layout, verbatim)
__global__ void repack_wf(const float* __restrict__ rk, unsigned short* __restrict__ wf) {
  int idx = blockIdx.x * 256 + threadIdx.x;  // 4g*4w*4G*8ks*64lane = 32768
  if (idx >= 32768) return;
  int lane = idx & 63, ks = (idx >> 6) & 7, G = (idx >> 9) & 3;
  int w = (idx >> 11) & 3, g = (idx >> 13) & 3;
  int ncol = G * 256 + g * 64 + 16 * w + (lane & 15);
  int kb = ks * 32 + ((lane >> 4) << 3);
  union { unsigned short s[8]; uint4 v; } u;
  #pragma unroll
  for (int e = 0; e < 8; ++e) u.s[e] = f2bf(rk[(size_t)(kb + e) * 1024 + ncol]);
  ((uint4*)wf)[idx] = u.v;
}

// ---- xw = x @ kernel ; BM=BN=128, BK=32, 256 thr, B split hi+lo (2 MFMAs) ----
__global__ __launch_bounds__(256, 2) void gemm_xw(
    const float* __restrict__ x, const unsigned short* __restrict__ wt_hi,
    const unsigned short* __restrict__ wt_lo, __half* __restrict__ xw) {
  __shared__ __align__(16) unsigned short As[128][40];
  __shared__ __align__(16) unsigned short Bh[128][40];
  __shared__ __align__(16) unsigned short Bl[128][40];
  const int tid = threadIdx.x;
  const int m0 = blockIdx.y << 7;
  const int n0 = blockIdx.x << 7;
  const int lane = tid & 63, wv = tid >> 6;
  const int wr = wv >> 1, wc = wv & 1;
  const int fm = lane & 15;
  const int fkb = (lane >> 4) << 3;
  const int sr = tid >> 1, sh = (tid & 1) << 4;
  f32x4 acc[4][4];
  #pragma unroll
  for (int a = 0; a < 4; ++a)
    #pragma unroll
    for (int b = 0; b < 4; ++b) acc[a][b] = (f32x4){0.f, 0.f, 0.f, 0.f};

  const float* xsrc = x + (size_t)(m0 + sr) * 784;
  const unsigned short* bhsrc = wt_hi + (size_t)(n0 + sr) * 800;
  const unsigned short* blsrc = wt_lo + (size_t)(n0 + sr) * 800;

  for (int kt = 0; kt < 25; ++kt) {
    const int kb = (kt << 5) + sh;
    float va[16];
    if (kb + 16 <= 784) {
      const float4* s = (const float4*)(xsrc + kb);
      #pragma unroll
      for (int q = 0; q < 4; ++q) {
        float4 f = s[q];
        va[q * 4 + 0] = f.x; va[q * 4 + 1] = f.y;
        va[q * 4 + 2] = f.z; va[q * 4 + 3] = f.w;
      }
    } else {
      #pragma unroll
      for (int q = 0; q < 16; ++q) va[q] = 0.f;
    }
    uint32_t pk[8];
    #pragma unroll
    for (int q = 0; q < 8; ++q)
      pk[q] = (uint32_t)f2bf(va[2 * q]) | ((uint32_t)f2bf(va[2 * q + 1]) << 16);
    uint4* adst = (uint4*)&As[sr][sh];
    adst[0] = make_uint4(pk[0], pk[1], pk[2], pk[3]);
    adst[1] = make_uint4(pk[4], pk[5], pk[6], pk[7]);
    const uint4* bh4 = (const uint4*)(bhsrc + kb);
    const uint4* bl4 = (const uint4*)(blsrc + kb);
    uint4* bhd = (uint4*)&Bh[sr][sh];
    uint4* bld = (uint4*)&Bl[sr][sh];
    bhd[0] = bh4[0]; bhd[1] = bh4[1];
    bld[0] = bl4[0]; bld[1] = bl4[1];
    __syncthreads();

    short8 af[4], bh[4], bl[4];
    #pragma unroll
    for (int mt = 0; mt < 4; ++mt)
      af[mt] = *(const short8*)&As[(wr << 6) + (mt << 4) + fm][fkb];
    #pragma unroll
    for (int nt = 0; nt < 4; ++nt) {
      bh[nt] = *(const short8*)&Bh[(wc << 6) + (nt << 4) + fm][fkb];
      bl[nt] = *(const short8*)&Bl[(wc << 6) + (nt << 4) + fm][fkb];
    }
    #pragma unroll
    for (int mt = 0; mt < 4; ++mt)
      #pragma unroll
      for (int nt = 0; nt < 4; ++nt) {
        acc[mt][nt] = __builtin_amdgcn_mfma_f32_16x16x32_bf16(af[mt], bh[nt], acc[mt][nt], 0, 0, 0);
        acc[mt][nt] = __builtin_amdgcn_mfma_f32_16x16x32_bf16(af[mt], bl[nt], acc[mt][nt], 0, 0, 0);
      }
    __syncthreads();
  }
  const int rbase = (lane >> 4) << 2;
  #pragma unroll
  for (int mt = 0; mt < 4; ++mt)
    #pragma unroll
    for (int nt = 0; nt < 4; ++nt) {
      int col = n0 + (wc << 6) + (nt << 4) + fm;
      #pragma unroll
      for (int r = 0; r < 4; ++r) {
        int row = m0 + (wr << 6) + (mt << 4) + rbase + r;
        xw[(size_t)row * 1024 + col] = __float2half(acc[mt][nt][r]);
      }
    }
}

// ---- persistent recurrent scan: LDS weights + batched-poll exchange ----
__global__ __launch_bounds__(256, 1) void scan_kernel(
    const unsigned short* __restrict__ wf, __half* __restrict__ xw,
    unsigned long long* __restrict__ pub,
    const float* __restrict__ bias, const float* __restrict__ wci,
    const float* __restrict__ wcf, const float* __restrict__ wco,
    const float* __restrict__ gamma, const float* __restrict__ beta,
    const float* __restrict__ mean, const float* __restrict__ var) {
  __shared__ __align__(16) unsigned short h_all[16][264];
  __shared__ __align__(16) uint4 wlds[8192];  // 128 KB: Wr slice, (w,G,ks,lane) frags
  const int tid = threadIdx.x, lane = tid & 63, w = tid >> 6;
  const int gr = blockIdx.x & 7;   // batch-group
  const int g = blockIdx.x >> 3;   // member: owns jj in [0,64) -> jg = 64g+jj
  const int c = lane & 15, q = lane >> 4;
  const int jj = 16 * w + c, jg = 64 * g + jj;

  // stage this WG's Wr slice into LDS once (layout preserved from repack_wf)
  {
    const uint4* src = (const uint4*)wf + (size_t)g * 8192;
    for (int i = tid; i < 8192; i += 256) wlds[i] = src[i];
  }
  const short8* wl8 = (const short8*)wlds;

  const float b0 = bias[jg], b1 = bias[256 + jg], b2 = bias[512 + jg], b3 = bias[768 + jg];
  const float pci = wci[jg], pcf = wcf[jg], pco = wco[jg];
  const float bna = gamma[jg] * rsqrtf(var[jg] + 1e-3f);
  const float bnb = beta[jg] - mean[jg] * bna;
  float c2[4] = {0.f, 0.f, 0.f, 0.f};

  unsigned long long* mypub = pub + (size_t)(gr * 4 + g) * 512 + jj * 8 + q * 2;
  // zero own words (both parities): no garbage-tag collisions from wt_hi overlay
  __hip_atomic_store(mypub + 0, 0ull, __ATOMIC_RELAXED, __HIP_MEMORY_SCOPE_SYSTEM);
  __hip_atomic_store(mypub + 1, 0ull, __ATOMIC_RELAXED, __HIP_MEMORY_SCOPE_SYSTEM);
  __hip_atomic_store(mypub + 16384, 0ull, __ATOMIC_RELAXED, __HIP_MEMORY_SCOPE_SYSTEM);
  __hip_atomic_store(mypub + 16385, 0ull, __ATOMIC_RELAXED, __HIP_MEMORY_SCOPE_SYSTEM);

  // peer word base addresses (this thread's own 2 words per peer)
  const unsigned long long* q0 = pub + (size_t)(gr * 4 + ((g + 1) & 3)) * 512 + 2 * tid;
  const unsigned long long* q1 = pub + (size_t)(gr * 4 + ((g + 2) & 3)) * 512 + 2 * tid;
  const unsigned long long* q2 = pub + (size_t)(gr * 4 + ((g + 3) & 3)) * 512 + 2 * tid;

  const size_t xbase = ((size_t)(gr * 16 + 4 * q) << 9);  // row of batch 4q, t=0

  // prefetch xw for s=0
  float xp[4][4];
  #pragma unroll
  for (int G = 0; G < 4; ++G)
    #pragma unroll
    for (int r = 0; r < 4; ++r)
      xp[G][r] = __half2float(xw[((xbase + ((size_t)r << 9)) << 10) + G * 256 + jg]);

  __syncthreads();  // wlds staged (once; full sync fine here)

  for (int s = 0; s < 512; ++s) {
    f32x4 acc[4];
    #pragma unroll
    for (int G = 0; G < 4; ++G) acc[G] = (f32x4){0.f, 0.f, 0.f, 0.f};

    if (s > 0) {
      // BATCHED poll: 6 unconditional relaxed loads issued back-to-back
      // (one waitcnt), then combined tag check — ~1 round trip per iteration
      // instead of 6 serialized ones (the R4-R8 wall).
      unsigned long long v0, v1, v2, v3, v4, v5;
      long cnt = 0;
      const size_t slot = (size_t)(s & 1) * 16384;
      const unsigned s32 = (unsigned)s;
      for (;;) {
        v0 = __hip_atomic_load(q0 + slot, __ATOMIC_RELAXED, __HIP_MEMORY_SCOPE_SYSTEM);
        v1 = __hip_atomic_load(q0 + slot + 1, __ATOMIC_RELAXED, __HIP_MEMORY_SCOPE_SYSTEM);
        v2 = __hip_atomic_load(q1 + slot, __ATOMIC_RELAXED, __HIP_MEMORY_SCOPE_SYSTEM);
        v3 = __hip_atomic_load(q1 + slot + 1, __ATOMIC_RELAXED, __HIP_MEMORY_SCOPE_SYSTEM);
        v4 = __hip_atomic_load(q2 + slot, __ATOMIC_RELAXED, __HIP_MEMORY_SCOPE_SYSTEM);
        v5 = __hip_atomic_load(q2 + slot + 1, __ATOMIC_RELAXED, __HIP_MEMORY_SCOPE_SYSTEM);
        bool ok = ((unsigned)(v0 >> 32) == s32) & ((unsigned)(v1 >> 32) == s32) &
                  ((unsigned)(v2 >> 32) == s32) & ((unsigned)(v3 >> 32) == s32) &
                  ((unsigned)(v4 >> 32) == s32) & ((unsigned)(v5 >> 32) == s32);
        if (ok) break;
        if (++cnt > (1L << 22)) break;  // bounded: no infinite hang
      }
      // stage peer h into h_all (bit = pp*2+u2 -> v[bit]; wid = 2*tid+u2)
      unsigned long long vv[6] = {v0, v1, v2, v3, v4, v5};
      #pragma unroll
      for (int pp = 0; pp < 3; ++pp) {
        int p = (g + 1 + pp) & 3;
        #pragma unroll
        for (int u2 = 0; u2 < 2; ++u2) {
          int wid = 2 * tid + u2;
          unsigned long long v = vv[pp * 2 + u2];
          int jj2 = wid >> 3, qq = (wid >> 1) & 3, uu = wid & 1;
          int m0 = 4 * qq + 2 * uu, col = 64 * p + jj2;
          h_all[m0][col] = (unsigned short)(v & 0xffffu);
          h_all[m0 + 1][col] = (unsigned short)((v >> 16) & 0xffffu);
        }
      }
      bar_raw();  // BAR-A: peer h visible (LDS only; vmem stays in flight)
      // z_rec = h(s) @ WrSlice — B-frags streamed from LDS (conflict-free b128)
      #pragma unroll
      for (int ks = 0; ks < 8; ++ks) {
        short8 afk = *(const short8*)&h_all[c][ks * 32 + q * 8];
        #pragma unroll
        for (int G = 0; G < 4; ++G) {
          short8 bfr = wl8[((w * 4 + G) * 8 + ks) * 64 + lane];
          acc[G] = __builtin_amdgcn_mfma_f32_16x16x32_bf16(afk, bfr, acc[G], 0, 0, 0);
        }
      }
      bar_raw();  // BAR-B: h_all reads done before overwrite below
    }

    // gates, directly in C-layout: lane owns (jj, batches 4q..4q+3)
    float hn[4];
    #pragma unroll
    for (int r = 0; r < 4; ++r) {
      float z0 = acc[0][r] + b0 + xp[0][r];
      float z1 = acc[1][r] + b1 + xp[1][r];
      float z2 = acc[2][r] + b2 + xp[2][r];
      float z3 = acc[3][r] + b3 + xp[3][r];
      float ig = sigm(z0 + c2[r] * pci);
      float fg = sigm(z1 + c2[r] * pcf);
      float cn = fg * c2[r] + ig * tanh_(z2);
      float og = sigm(z3 + cn * pco);
      float h = og * tanh_(cn);
      c2[r] = cn;
      hn[r] = h;
      if ((r & 1) && s < 511) {  // publish pair ASAP: overlaps remaining gates
        unsigned long long pv =
            ((unsigned long long)(unsigned)(s + 1) << 32) |
            (unsigned long long)(((uint32_t)f2bf(hn[r - 1])) |
                                 ((uint32_t)f2bf(hn[r]) << 16));
        __hip_atomic_store(mypub + (size_t)((s + 1) & 1) * 16384 + (r >> 1), pv,
                           __ATOMIC_RELAXED, __HIP_MEMORY_SCOPE_SYSTEM);
      }
    }
    #pragma unroll
    for (int r = 0; r < 4; ++r) h_all[4 * q + r][jg] = f2bf(hn[r]);
    // y = tanh(BN(h)) -> xw col jg (final FC reads later)
    #pragma unroll
    for (int r = 0; r < 4; ++r) {
      float y = tanh_(hn[r] * bna + bnb);
      xw[((xbase + ((size_t)r << 9) + s) << 10) + jg] = __float2half(y);
    }
    // prefetch xw for s+1 (latency hidden under next poll/MFMA; no drain now)
    if (s < 511) {
      #pragma unroll
      for (int G = 0; G < 4; ++G)
        #pragma unroll
        for (int r = 0; r < 4; ++r)
          xp[G][r] = __half2float(
              xw[((xbase + ((size_t)r << 9) + (s + 1)) << 10) + G * 256 + jg]);
    }
  }
}

// ---- final FC: out[b,t,c] = sum_j y[b,t,j] * fcw[j,c]; wave per row ----
__global__ __launch_bounds__(256) void final_fc(const __half* __restrict__ xw,
                                                const float* __restrict__ fcw,
                                                float* __restrict__ out) {
  const int tid = threadIdx.x, lane = tid & 63, w = tid >> 6;
  const int wid = blockIdx.x * 4 + w;  // 512 waves
  float fw[4][10];
  #pragma unroll
  for (int q = 0; q < 4; ++q)
    #pragma unroll
    for (int c = 0; c < 10; ++c) fw[q][c] = fcw[(lane * 4 + q) * 10 + c];
  for (int it = 0; it < 128; ++it) {
    const int row = it * 512 + wid;
    uint2 u = *(const uint2*)(xw + ((size_t)row << 10) + lane * 4);
    const __half* hp = (const __half*)&u;
    float y0 = __half2float(hp[0]), y1 = __half2float(hp[1]);
    float y2 = __half2float(hp[2]), y3 = __half2float(hp[3]);
    float p[10];
    #pragma unroll
    for (int c = 0; c < 10; ++c)
      p[c] = y0 * fw[0][c] + y1 * fw[1][c] + y2 * fw[2][c] + y3 * fw[3][c];
    #pragma unroll
    for (int off = 1; off < 64; off <<= 1)
      #pragma unroll
      for (int c = 0; c < 10; ++c) p[c] += __shfl_xor(p[c], off, 64);
    if (lane == 0) {
      #pragma unroll
      for (int c = 0; c < 10; ++c) out[(size_t)row * 10 + c] = p[c];
    }
  }
}

extern "C" void kernel_launch(void* const* d_in, const int* in_sizes, int n_in,
                              void* d_out, int out_size, void* d_ws, size_t ws_size,
                              hipStream_t stream) {
  const float* x     = (const float*)d_in[0];
  const float* kw    = (const float*)d_in[1];
  const float* rk    = (const float*)d_in[2];
  const float* bias  = (const float*)d_in[3];
  const float* wci   = (const float*)d_in[4];
  const float* wcf   = (const float*)d_in[5];
  const float* wco   = (const float*)d_in[6];
  const float* gamma = (const float*)d_in[7];
  const float* beta  = (const float*)d_in[8];
  const float* mean  = (const float*)d_in[9];
  const float* var   = (const float*)d_in[10];
  const float* fcw   = (const float*)d_in[11];
  float* out = (float*)d_out;

  char* ws = (char*)d_ws;
  __half*         xw    = (__half*)ws;                                 // 134217728 B
  unsigned short* wt_hi = (unsigned short*)(ws + 134217728);           // 1638400 B
  unsigned short* wt_lo = (unsigned short*)(ws + 134217728 + 1638400); // 1638400 B
  unsigned short* wfrag = (unsigned short*)(ws + 134217728 + 3276800); // 524288 B
  // pub overlays wt_hi (dead after gemm_xw): 2 parity * 32 WG * 512 u64 = 262144 B
  unsigned long long* pub = (unsigned long long*)(ws + 134217728);

  repack_w<<<dim3((1024 * 800 + 255) / 256), dim3(256), 0, stream>>>(kw, wt_hi, wt_lo);
  repack_wf<<<dim3(128), dim3(256), 0, stream>>>(rk, wfrag);
  gemm_xw<<<dim3(8, 512), dim3(256), 0, stream>>>(x, wt_hi, wt_lo, xw);
  scan_kernel<<<dim3(32), dim3(256), 0, stream>>>(wfrag, xw, pub, bias,
                                                  wci, wcf, wco, gamma, beta, mean, var);
  final_fc<<<dim3(128), dim3(256), 0, stream>>>(xw, fcw, out);
}